// Round 1
// 421.027 us; speedup vs baseline: 1.5239x; 1.5239x over previous
//
#include <hip/hip_runtime.h>
#include <math.h>

// Problem constants
#define BB 16
#define NN 4096
#define DD 256
#define CC 8
#define KK 512
#define SD 32
#define NTOK (BB * NN)            // 65536
#define IDS_N (NTOK * CC)         // 524288
#define QN (NTOK * DD)            // 16777216
#define OFF_Q   (IDS_N)
#define OFF_ST  (IDS_N + QN)
#define OFF_SC  (IDS_N + 2 * QN)

// Margin gate: split-bf16 3-MFMA score error <= ~8e-6 worst case; np-vs-exact
// flip requires exact gap <= ~1.6e-5. Unflagged => fast gap >= GUARD =>
// exact gap >= 6e-5 - 1.6e-5 = 4.4e-5 > 1.6e-5 (2.7x margin). ~1.5% flagged.
#define GUARD 6e-5f
#define CAP 65536

// ws layout
// 0:   double mse_sum
// 8:   double mask_sum
// 16:  unsigned flag_count (+pad)
// 32:  float hist[CC*KK]            (16384 B)
// 32+16384: float csqf[CC*KK]       (16384 B)
// 32+32768: unsigned list[CAP]      (262144 B)
#define WS_ZERO (32 + 16384)

typedef float f32x4 __attribute__((ext_vector_type(4)));
typedef short s16x8 __attribute__((ext_vector_type(8)));

__device__ __forceinline__ unsigned short f2bf(float f) {
    unsigned u = __float_as_uint(f);
    u += 0x7fffu + ((u >> 16) & 1u);
    return (unsigned short)(u >> 16);
}
__device__ __forceinline__ float bf2f(unsigned short h) {
    return __uint_as_float(((unsigned)h) << 16);
}
// split f32x8 -> bf16 hi + bf16 lo (x ~= hi + lo, exact to 2^-16 rel)
__device__ __forceinline__ void split8(const float4 a, const float4 b,
                                       s16x8& hv, s16x8& lv) {
    unsigned short h;
    h = f2bf(a.x); hv[0]=(short)h; lv[0]=(short)f2bf(a.x - bf2f(h));
    h = f2bf(a.y); hv[1]=(short)h; lv[1]=(short)f2bf(a.y - bf2f(h));
    h = f2bf(a.z); hv[2]=(short)h; lv[2]=(short)f2bf(a.z - bf2f(h));
    h = f2bf(a.w); hv[3]=(short)h; lv[3]=(short)f2bf(a.w - bf2f(h));
    h = f2bf(b.x); hv[4]=(short)h; lv[4]=(short)f2bf(b.x - bf2f(h));
    h = f2bf(b.y); hv[5]=(short)h; lv[5]=(short)f2bf(b.y - bf2f(h));
    h = f2bf(b.z); hv[6]=(short)h; lv[6]=(short)f2bf(b.z - bf2f(h));
    h = f2bf(b.w); hv[7]=(short)h; lv[7]=(short)f2bf(b.w - bf2f(h));
}

// ---------------------------------------------------------------------------
// Prep: csq (f64-accurate -> f32, same fma order as the verified kernel),
// plus parallel mask-sum.
__global__ __launch_bounds__(256) void vq_prep(
    const float* __restrict__ cbs, const float* __restrict__ mask,
    float* __restrict__ csqf, double* __restrict__ mask_sum)
{
    __shared__ double red[256];
    const int tid = threadIdx.x;
    const int cell = blockIdx.x * 256 + tid;     // 16 blocks -> 4096 cells
    const float* cp = cbs + (size_t)cell * SD;
    double s = 0.0;
    #pragma unroll
    for (int j = 0; j < 8; ++j) {
        float4 v = ((const float4*)cp)[j];
        double a = (double)v.x, b = (double)v.y, c = (double)v.z, d = (double)v.w;
        s = fma(a, a, s); s = fma(b, b, s);
        s = fma(c, c, s); s = fma(d, d, s);
    }
    csqf[cell] = (float)s;

    double m = 0.0;
    for (int i = cell; i < NTOK; i += 4096) m += (double)mask[i];
    red[tid] = m;
    __syncthreads();
    for (int st = 128; st > 0; st >>= 1) {
        if (tid < st) red[tid] += red[tid + st];
        __syncthreads();
    }
    if (tid == 0) atomicAdd(mask_sum, red[0]);
}

// ---------------------------------------------------------------------------
// MFMA fast pass. Block = 512 thr (8 waves) handles one codebook c and a
// 1024-token slab in 4 passes of 8x32 tokens. Codebook staged in LDS as
// split-bf16; scores via 3x mfma_f32_16x16x32_bf16 (hi*hi + hi*lo + lo*hi),
// f32-accurate to ~8e-6. Top-2 per token tracked per-lane, merged across the
// 16-lane column groups; pairs with margin < GUARD deferred to vq_resolve.
__global__ __launch_bounds__(512, 4) void vq_score(
    const float* __restrict__ latents, const float* __restrict__ mask,
    const float* __restrict__ cbs, const float* __restrict__ csq_g,
    float* __restrict__ out, double* __restrict__ mse_sum,
    float* __restrict__ hist, unsigned* __restrict__ count,
    unsigned* __restrict__ list)
{
    __shared__ unsigned short s_hi[KK * SD];   // 32 KB
    __shared__ unsigned short s_lo[KK * SD];   // 32 KB
    __shared__ float  s_csq[KK];               // 2 KB
    __shared__ float  s_lhist[KK];             // 2 KB
    __shared__ float  s_best[8][32];
    __shared__ float  s_sec[8][32];
    __shared__ int    s_bid[8][32];
    __shared__ double s_mse[8];

    const int tid = threadIdx.x;
    const int c   = blockIdx.x & 7;
    const int tb  = blockIdx.x >> 3;           // 0..63

    // ---- stage codebook c (split-bf16) + csq + zero local hist ----
    {
        const int cw = tid;                    // 512 threads == KK codewords
        const float* cp = cbs + ((size_t)c * KK + cw) * SD;
        s_csq[cw] = csq_g[c * KK + cw];
        s_lhist[cw] = 0.f;
        #pragma unroll
        for (int q = 0; q < 4; ++q) {
            float4 a = ((const float4*)cp)[2 * q];
            float4 b = ((const float4*)cp)[2 * q + 1];
            s16x8 hv, lv;
            split8(a, b, hv, lv);
            ((s16x8*)(s_hi + (size_t)cw * SD))[q] = hv;
            ((s16x8*)(s_lo + (size_t)cw * SD))[q] = lv;
        }
    }
    __syncthreads();

    const int wv   = tid >> 6;                 // wave 0..7
    const int lane = tid & 63;
    const int col  = lane & 15;                // A-row / B-col / C-col
    const int kb   = lane >> 4;                // k-group 0..3

    double mseTot = 0.0;

    #pragma unroll 1
    for (int p = 0; p < 4; ++p) {
        const int tok0 = tb * 1024 + p * 256 + wv * 32;

        // A fragments for 2 row-tiles: lane holds token (tok0+t*16+col),
        // dims k = kb*8 .. kb*8+7 of codebook slice c.
        s16x8 ah[2], al[2];
        #pragma unroll
        for (int t = 0; t < 2; ++t) {
            const int token = tok0 + t * 16 + col;
            const float4* xp =
                (const float4*)(latents + (size_t)token * DD + c * SD + kb * 8);
            split8(xp[0], xp[1], ah[t], al[t]);
        }

        float best[2][4], sec[2][4]; int bid[2][4];
        #pragma unroll
        for (int t = 0; t < 2; ++t)
            #pragma unroll
            for (int r = 0; r < 4; ++r) {
                best[t][r] = 1e30f; sec[t][r] = 1e30f; bid[t][r] = 0;
            }

        for (int nt = 0; nt < 32; ++nt) {
            const int kcol = nt * 16 + col;    // this lane's codeword column
            const float cs = s_csq[kcol];
            const s16x8 bh = *((const s16x8*)(s_hi + (size_t)kcol * SD + kb * 8));
            const s16x8 bl = *((const s16x8*)(s_lo + (size_t)kcol * SD + kb * 8));
            #pragma unroll
            for (int t = 0; t < 2; ++t) {
                f32x4 acc = {0.f, 0.f, 0.f, 0.f};
                acc = __builtin_amdgcn_mfma_f32_16x16x32_bf16(ah[t], bh, acc, 0, 0, 0);
                acc = __builtin_amdgcn_mfma_f32_16x16x32_bf16(ah[t], bl, acc, 0, 0, 0);
                acc = __builtin_amdgcn_mfma_f32_16x16x32_bf16(al[t], bh, acc, 0, 0, 0);
                // acc[r] = dot(token row kb*4+r, codeword kcol)
                #pragma unroll
                for (int r = 0; r < 4; ++r) {
                    const float s = fmaf(-2.f, acc[r], cs);
                    const bool lt = s < best[t][r];
                    bid[t][r]  = lt ? kcol : bid[t][r];
                    sec[t][r]  = fminf(sec[t][r], fmaxf(s, best[t][r]));
                    best[t][r] = fminf(best[t][r], s);
                }
            }
        }

        // merge top-2 across the 16 lanes of each kb-group (exact ties ->
        // gap 0 -> flagged, so tie semantics are safe)
        #pragma unroll
        for (int m = 1; m <= 8; m <<= 1) {
            #pragma unroll
            for (int t = 0; t < 2; ++t)
                #pragma unroll
                for (int r = 0; r < 4; ++r) {
                    const float ob = __shfl_xor(best[t][r], m, 64);
                    const float os = __shfl_xor(sec[t][r],  m, 64);
                    const int   oi = __shfl_xor(bid[t][r],  m, 64);
                    const float ns = fminf(fmaxf(best[t][r], ob),
                                           fminf(sec[t][r], os));
                    const bool tk = (ob < best[t][r]) ||
                                    (ob == best[t][r] && oi < bid[t][r]);
                    bid[t][r]  = tk ? oi : bid[t][r];
                    best[t][r] = fminf(best[t][r], ob);
                    sec[t][r]  = ns;
                }
        }

        // publish per-token results to wave-private LDS scratch
        asm volatile("s_waitcnt lgkmcnt(0)" ::: "memory");
        if (col == 0) {
            #pragma unroll
            for (int t = 0; t < 2; ++t)
                #pragma unroll
                for (int r = 0; r < 4; ++r) {
                    const int idx = t * 16 + kb * 4 + r;
                    s_best[wv][idx] = best[t][r];
                    s_sec[wv][idx]  = sec[t][r];
                    s_bid[wv][idx]  = bid[t][r];
                }
        }
        asm volatile("s_waitcnt lgkmcnt(0)" ::: "memory");

        // ---- epilogue: 2 lanes per token, 16 dims each ----
        const int tl    = lane >> 1;
        const int half  = lane & 1;
        const int token = tok0 + tl;
        const float bb  = s_best[wv][tl];
        const float ssv = s_sec[wv][tl];
        const int   bi  = s_bid[wv][tl];
        const bool flag = (ssv - bb) < GUARD;

        const float* qp = cbs + ((size_t)c * KK + bi) * SD + half * 16;
        const float* xp = latents + (size_t)token * DD + c * SD + half * 16;
        float* oq  = out + OFF_Q  + (size_t)token * DD + c * SD + half * 16;
        float* ost = out + OFF_ST + (size_t)token * DD + c * SD + half * 16;
        double acc = 0.0;
        #pragma unroll
        for (int j = 0; j < 4; ++j) {
            float4 qv = ((const float4*)qp)[j];
            float4 xv = ((const float4*)xp)[j];
            float4 sv;
            sv.x = xv.x + (qv.x - xv.x);
            sv.y = xv.y + (qv.y - xv.y);
            sv.z = xv.z + (qv.z - xv.z);
            sv.w = xv.w + (qv.w - xv.w);
            double d;
            d = (double)xv.x - (double)qv.x; acc = fma(d, d, acc);
            d = (double)xv.y - (double)qv.y; acc = fma(d, d, acc);
            d = (double)xv.z - (double)qv.z; acc = fma(d, d, acc);
            d = (double)xv.w - (double)qv.w; acc = fma(d, d, acc);
            ((float4*)oq)[j]  = qv;
            ((float4*)ost)[j] = sv;
        }
        if (!flag) mseTot += acc;
        if (half == 0) {
            out[(size_t)token * CC + c] = (float)bi;
            if (!flag) {
                atomicAdd(&s_lhist[bi], mask[token]);
            } else {
                unsigned slot = atomicAdd(count, 1u);
                if (slot < CAP) list[slot] = ((unsigned)token << 3) | (unsigned)c;
            }
        }
    }

    // ---- block reductions: mse + local hist flush ----
    #pragma unroll
    for (int off = 32; off > 0; off >>= 1)
        mseTot += __shfl_down(mseTot, off, 64);
    if (lane == 0) s_mse[wv] = mseTot;
    __syncthreads();
    if (tid == 0) {
        double s = 0.0;
        #pragma unroll
        for (int w = 0; w < 8; ++w) s += s_mse[w];
        atomicAdd(mse_sum, s);
    }
    {
        float v = s_lhist[tid];
        if (v != 0.f) atomicAdd(&hist[c * KK + tid], v);
    }
}

// ---------------------------------------------------------------------------
// Exact re-resolve: one wave per flagged (token,c). Replicates the verified
// arithmetic bit-for-bit (f64 subterms -> single f32 rounding, np first-index
// tie-break), then patches ids/quant/st if changed and adds hist/mse.
__global__ __launch_bounds__(256) void vq_resolve(
    const float* __restrict__ latents, const float* __restrict__ mask,
    const float* __restrict__ cbs, const float* __restrict__ csq_g,
    float* __restrict__ out, double* __restrict__ mse_sum,
    float* __restrict__ hist, const unsigned* __restrict__ count,
    const unsigned* __restrict__ list)
{
    unsigned n = *count; if (n > CAP) n = CAP;
    const int lane  = threadIdx.x & 63;
    const int wave  = (blockIdx.x << 2) | (threadIdx.x >> 6);
    const int nwav  = gridDim.x << 2;

    for (unsigned i = wave; i < n; i += nwav) {
        const unsigned e = list[i];
        const int token = (int)(e >> 3), c = (int)(e & 7u);
        const float* xp = latents + (size_t)token * DD + c * SD;

        double xd[SD]; double xs = 0.0;
        #pragma unroll
        for (int j = 0; j < 8; ++j) {
            float4 v = ((const float4*)xp)[j];
            xd[4*j+0] = (double)v.x; xd[4*j+1] = (double)v.y;
            xd[4*j+2] = (double)v.z; xd[4*j+3] = (double)v.w;
            xs = fma((double)v.x, (double)v.x, xs);
            xs = fma((double)v.y, (double)v.y, xs);
            xs = fma((double)v.z, (double)v.z, xs);
            xs = fma((double)v.w, (double)v.w, xs);
        }
        const float xsqf = (float)xs;
        const float* cbase = cbs + (size_t)c * KK * SD;
        const float* csqc  = csq_g + c * KK;

        float best = 1e30f; int bk = lane * 8;
        for (int j = 0; j < 8; ++j) {
            const int k = lane * 8 + j;
            const float* cw = cbase + k * SD;
            double d0 = 0.0, d1 = 0.0, d2 = 0.0, d3 = 0.0;
            #pragma unroll
            for (int q = 0; q < 8; ++q) {
                d0 = fma((double)cw[4*q+0], xd[4*q+0], d0);
                d1 = fma((double)cw[4*q+1], xd[4*q+1], d1);
                d2 = fma((double)cw[4*q+2], xd[4*q+2], d2);
                d3 = fma((double)cw[4*q+3], xd[4*q+3], d3);
            }
            const float dotf = (float)((d0 + d1) + (d2 + d3));
            const float t1 = xsqf + csqc[k];
            const float dist = t1 - 2.0f * dotf;
            if (dist < best) { best = dist; bk = k; }
        }
        #pragma unroll
        for (int off = 32; off > 0; off >>= 1) {
            float od = __shfl_down(best, off, 64);
            int   ok = __shfl_down(bk,   off, 64);
            if (od < best || (od == best && ok < bk)) { best = od; bk = ok; }
        }
        bk = __shfl(bk, 0, 64);

        const int oldid = (int)out[(size_t)token * CC + c];
        if (bk != oldid) {
            if (lane == 0) out[(size_t)token * CC + c] = (float)bk;
            if (lane < SD) {
                float q = cbase[bk * SD + lane];
                float x = xp[lane];
                out[OFF_Q  + (size_t)token * DD + c * SD + lane] = q;
                out[OFF_ST + (size_t)token * DD + c * SD + lane] = x + (q - x);
            }
        }
        double dd = 0.0;
        if (lane < SD) {
            double q = (double)cbase[bk * SD + lane];
            double df = (double)xp[lane] - q;
            dd = df * df;
        }
        #pragma unroll
        for (int off = 32; off > 0; off >>= 1) dd += __shfl_down(dd, off, 64);
        if (lane == 0) {
            atomicAdd(mse_sum, dd);
            atomicAdd(&hist[c * KK + bk], mask[token]);
        }
    }
}

// ---------------------------------------------------------------------------
__global__ __launch_bounds__(512) void vq_final(
    const float* __restrict__ hist, const double* __restrict__ mse_sum,
    const double* __restrict__ mask_sum, float* __restrict__ out)
{
    __shared__ double ent[CC];
    const int tid = threadIdx.x;
    double denom = *mask_sum; if (denom < 1.0) denom = 1.0;

    const int w = tid >> 6;
    const int lane = tid & 63;
    double t = 0.0;
    for (int k = lane; k < KK; k += 64) {
        double p = (double)hist[w * KK + k] / denom;
        t += p * log(p + 1e-8);
    }
    #pragma unroll
    for (int off = 32; off > 0; off >>= 1) t += __shfl_down(t, off, 64);
    if (lane == 0) ent[w] = -t;
    __syncthreads();

    if (tid == 0) {
        double mean = mse_sum[0] / (double)QN;
        out[OFF_SC + 0] = (float)(0.25 * mean);
        out[OFF_SC + 1] = (float)(1.0 * mean);
        double perp = 0.0;
        for (int cc = 0; cc < CC; ++cc) perp += exp(ent[cc]);
        out[OFF_SC + 2] = (float)(perp / (double)CC);
    }
}

extern "C" void kernel_launch(void* const* d_in, const int* in_sizes, int n_in,
                              void* d_out, int out_size, void* d_ws, size_t ws_size,
                              hipStream_t stream) {
    const float* latents = (const float*)d_in[0];
    const float* mask    = (const float*)d_in[1];
    const float* cbs     = (const float*)d_in[2];
    float* out = (float*)d_out;

    double*   mse      = (double*)d_ws;
    double*   mask_sum = (double*)((char*)d_ws + 8);
    unsigned* count    = (unsigned*)((char*)d_ws + 16);
    float*    hist     = (float*)((char*)d_ws + 32);
    float*    csqf     = (float*)((char*)d_ws + 32 + 16384);
    unsigned* list     = (unsigned*)((char*)d_ws + 32 + 32768);

    hipMemsetAsync(d_ws, 0, WS_ZERO, stream);

    vq_prep<<<dim3(16), dim3(256), 0, stream>>>(cbs, mask, csqf, mask_sum);
    vq_score<<<dim3(512), dim3(512), 0, stream>>>(
        latents, mask, cbs, csqf, out, mse, hist, count, list);
    vq_resolve<<<dim3(512), dim3(256), 0, stream>>>(
        latents, mask, cbs, csqf, out, mse, hist, count, list);
    vq_final<<<dim3(1), dim3(512), 0, stream>>>(hist, mse, mask_sum, out);
}

// Round 2
// 410.364 us; speedup vs baseline: 1.5635x; 1.0260x over previous
//
#include <hip/hip_runtime.h>
#include <math.h>

// Problem constants
#define BB 16
#define NN 4096
#define DD 256
#define CC 8
#define KK 512
#define SD 32
#define NTOK (BB * NN)            // 65536
#define IDS_N (NTOK * CC)         // 524288
#define QN (NTOK * DD)            // 16777216
#define OFF_Q   (IDS_N)
#define OFF_ST  (IDS_N + QN)
#define OFF_SC  (IDS_N + 2 * QN)

// Margin gate: split-bf16 3-MFMA score error <= ~8e-6 worst case; np-vs-exact
// flip requires exact gap <= ~1.6e-5. Unflagged => fast gap >= GUARD =>
// exact gap >= 6e-5 - 1.6e-5 = 4.4e-5 > 1.6e-5 (2.7x margin). ~1.5% flagged.
#define GUARD 6e-5f
#define CAP 65536

// ws layout
// 0:   double mse_sum
// 8:   double mask_sum
// 16:  unsigned flag_count (+pad)
// 32:  float hist[CC*KK]            (16384 B)
// 32+16384: float csqf[CC*KK]       (16384 B)
// 32+32768: unsigned list[CAP]      (262144 B)
#define WS_ZERO (32 + 16384)

typedef float f32x4 __attribute__((ext_vector_type(4)));
typedef short s16x8 __attribute__((ext_vector_type(8)));

__device__ __forceinline__ unsigned short f2bf(float f) {
    unsigned u = __float_as_uint(f);
    u += 0x7fffu + ((u >> 16) & 1u);
    return (unsigned short)(u >> 16);
}
__device__ __forceinline__ float bf2f(unsigned short h) {
    return __uint_as_float(((unsigned)h) << 16);
}
// split f32x8 -> bf16 hi + bf16 lo (x ~= hi + lo, exact to 2^-16 rel)
__device__ __forceinline__ void split8(const float4 a, const float4 b,
                                       s16x8& hv, s16x8& lv) {
    unsigned short h;
    h = f2bf(a.x); hv[0]=(short)h; lv[0]=(short)f2bf(a.x - bf2f(h));
    h = f2bf(a.y); hv[1]=(short)h; lv[1]=(short)f2bf(a.y - bf2f(h));
    h = f2bf(a.z); hv[2]=(short)h; lv[2]=(short)f2bf(a.z - bf2f(h));
    h = f2bf(a.w); hv[3]=(short)h; lv[3]=(short)f2bf(a.w - bf2f(h));
    h = f2bf(b.x); hv[4]=(short)h; lv[4]=(short)f2bf(b.x - bf2f(h));
    h = f2bf(b.y); hv[5]=(short)h; lv[5]=(short)f2bf(b.y - bf2f(h));
    h = f2bf(b.z); hv[6]=(short)h; lv[6]=(short)f2bf(b.z - bf2f(h));
    h = f2bf(b.w); hv[7]=(short)h; lv[7]=(short)f2bf(b.w - bf2f(h));
}

// ---------------------------------------------------------------------------
// Prep: csq (f64-accurate -> f32, same fma order as the verified kernel),
// plus parallel mask-sum.
__global__ __launch_bounds__(256) void vq_prep(
    const float* __restrict__ cbs, const float* __restrict__ mask,
    float* __restrict__ csqf, double* __restrict__ mask_sum)
{
    __shared__ double red[256];
    const int tid = threadIdx.x;
    const int cell = blockIdx.x * 256 + tid;     // 16 blocks -> 4096 cells
    const float* cp = cbs + (size_t)cell * SD;
    double s = 0.0;
    #pragma unroll
    for (int j = 0; j < 8; ++j) {
        float4 v = ((const float4*)cp)[j];
        double a = (double)v.x, b = (double)v.y, c = (double)v.z, d = (double)v.w;
        s = fma(a, a, s); s = fma(b, b, s);
        s = fma(c, c, s); s = fma(d, d, s);
    }
    csqf[cell] = (float)s;

    double m = 0.0;
    for (int i = cell; i < NTOK; i += 4096) m += (double)mask[i];
    red[tid] = m;
    __syncthreads();
    for (int st = 128; st > 0; st >>= 1) {
        if (tid < st) red[tid] += red[tid + st];
        __syncthreads();
    }
    if (tid == 0) atomicAdd(mask_sum, red[0]);
}

// ---------------------------------------------------------------------------
// MFMA fast pass. Block = 512 thr (8 waves) handles one codebook c and a
// 1024-token slab in 4 passes of 8x32 tokens. Codebook staged in LDS as
// split-bf16 with a 16B-sub-block XOR swizzle (slot = kb ^ ((kcol>>1)&3));
// unswizzled layout is an 8-way bank conflict on every ds_read_b128.
// Scores via 3x mfma_f32_16x16x32_bf16; pairs with margin < GUARD deferred.
__global__ __launch_bounds__(512, 4) void vq_score(
    const float* __restrict__ latents, const float* __restrict__ mask,
    const float* __restrict__ cbs, const float* __restrict__ csq_g,
    float* __restrict__ out, double* __restrict__ mse_sum,
    float* __restrict__ hist, unsigned* __restrict__ count,
    unsigned* __restrict__ list)
{
    __shared__ unsigned short s_hi[KK * SD];   // 32 KB
    __shared__ unsigned short s_lo[KK * SD];   // 32 KB
    __shared__ float  s_csq[KK];               // 2 KB
    __shared__ float  s_lhist[KK];             // 2 KB
    __shared__ float  s_best[8][32];
    __shared__ float  s_sec[8][32];
    __shared__ int    s_bid[8][32];
    __shared__ double s_mse[8];

    const int tid = threadIdx.x;
    const int c   = blockIdx.x & 7;
    const int tb  = blockIdx.x >> 3;           // 0..63

    // ---- stage codebook c (split-bf16, swizzled) + csq + zero local hist ----
    {
        const int cw = tid;                    // 512 threads == KK codewords
        const float* cp = cbs + ((size_t)c * KK + cw) * SD;
        s_csq[cw] = csq_g[c * KK + cw];
        s_lhist[cw] = 0.f;
        const int sw = (cw >> 1) & 3;
        #pragma unroll
        for (int q = 0; q < 4; ++q) {
            float4 a = ((const float4*)cp)[2 * q];
            float4 b = ((const float4*)cp)[2 * q + 1];
            s16x8 hv, lv;
            split8(a, b, hv, lv);
            ((s16x8*)(s_hi + (size_t)cw * SD))[q ^ sw] = hv;
            ((s16x8*)(s_lo + (size_t)cw * SD))[q ^ sw] = lv;
        }
    }
    __syncthreads();

    const int wv   = tid >> 6;                 // wave 0..7
    const int lane = tid & 63;
    const int col  = lane & 15;                // A-row / B-col / C-col
    const int kb   = lane >> 4;                // k-group 0..3

    double mseTot = 0.0;

    #pragma unroll 1
    for (int p = 0; p < 4; ++p) {
        const int tok0 = tb * 1024 + p * 256 + wv * 32;

        // A fragments for 2 row-tiles: lane holds token (tok0+t*16+col),
        // dims k = kb*8 .. kb*8+7 of codebook slice c.
        s16x8 ah[2], al[2];
        #pragma unroll
        for (int t = 0; t < 2; ++t) {
            const int token = tok0 + t * 16 + col;
            const float4* xp =
                (const float4*)(latents + (size_t)token * DD + c * SD + kb * 8);
            split8(xp[0], xp[1], ah[t], al[t]);
        }

        float best[2][4], sec[2][4]; int bid[2][4];
        #pragma unroll
        for (int t = 0; t < 2; ++t)
            #pragma unroll
            for (int r = 0; r < 4; ++r) {
                best[t][r] = 1e30f; sec[t][r] = 1e30f; bid[t][r] = 0;
            }

        for (int nt = 0; nt < 32; ++nt) {
            const int kcol = nt * 16 + col;    // this lane's codeword column
            const int slot = kb ^ ((kcol >> 1) & 3);
            const float cs = s_csq[kcol];
            const s16x8 bh = *((const s16x8*)(s_hi + (size_t)kcol * SD + slot * 8));
            const s16x8 bl = *((const s16x8*)(s_lo + (size_t)kcol * SD + slot * 8));
            #pragma unroll
            for (int t = 0; t < 2; ++t) {
                f32x4 acc = {0.f, 0.f, 0.f, 0.f};
                acc = __builtin_amdgcn_mfma_f32_16x16x32_bf16(ah[t], bh, acc, 0, 0, 0);
                acc = __builtin_amdgcn_mfma_f32_16x16x32_bf16(ah[t], bl, acc, 0, 0, 0);
                acc = __builtin_amdgcn_mfma_f32_16x16x32_bf16(al[t], bh, acc, 0, 0, 0);
                // acc[r] = dot(token row kb*4+r, codeword kcol)
                #pragma unroll
                for (int r = 0; r < 4; ++r) {
                    const float s = fmaf(-2.f, acc[r], cs);
                    const bool lt = s < best[t][r];
                    bid[t][r]  = lt ? kcol : bid[t][r];
                    // invariant sec >= best, so median(s, best, sec) is the
                    // exact new runner-up
                    sec[t][r]  = __builtin_amdgcn_fmed3f(s, best[t][r], sec[t][r]);
                    best[t][r] = fminf(best[t][r], s);
                }
            }
        }

        // merge top-2 across the 16 lanes of each kb-group (exact ties ->
        // gap 0 -> flagged, so tie semantics are safe)
        #pragma unroll
        for (int m = 1; m <= 8; m <<= 1) {
            #pragma unroll
            for (int t = 0; t < 2; ++t)
                #pragma unroll
                for (int r = 0; r < 4; ++r) {
                    const float ob = __shfl_xor(best[t][r], m, 64);
                    const float os = __shfl_xor(sec[t][r],  m, 64);
                    const int   oi = __shfl_xor(bid[t][r],  m, 64);
                    const float ns = fminf(fmaxf(best[t][r], ob),
                                           fminf(sec[t][r], os));
                    const bool tk = (ob < best[t][r]) ||
                                    (ob == best[t][r] && oi < bid[t][r]);
                    bid[t][r]  = tk ? oi : bid[t][r];
                    best[t][r] = fminf(best[t][r], ob);
                    sec[t][r]  = ns;
                }
        }

        // publish per-token results to wave-private LDS scratch
        asm volatile("s_waitcnt lgkmcnt(0)" ::: "memory");
        if (col == 0) {
            #pragma unroll
            for (int t = 0; t < 2; ++t)
                #pragma unroll
                for (int r = 0; r < 4; ++r) {
                    const int idx = t * 16 + kb * 4 + r;
                    s_best[wv][idx] = best[t][r];
                    s_sec[wv][idx]  = sec[t][r];
                    s_bid[wv][idx]  = bid[t][r];
                }
        }
        asm volatile("s_waitcnt lgkmcnt(0)" ::: "memory");

        // ---- epilogue: 2 lanes per token, 16 dims each ----
        const int tl    = lane >> 1;
        const int half  = lane & 1;
        const int token = tok0 + tl;
        const float bb  = s_best[wv][tl];
        const float ssv = s_sec[wv][tl];
        const int   bi  = s_bid[wv][tl];
        const bool flag = (ssv - bb) < GUARD;

        const float* qp = cbs + ((size_t)c * KK + bi) * SD + half * 16;
        const float* xp = latents + (size_t)token * DD + c * SD + half * 16;
        float* oq  = out + OFF_Q  + (size_t)token * DD + c * SD + half * 16;
        float* ost = out + OFF_ST + (size_t)token * DD + c * SD + half * 16;
        double acc = 0.0;
        #pragma unroll
        for (int j = 0; j < 4; ++j) {
            float4 qv = ((const float4*)qp)[j];
            float4 xv = ((const float4*)xp)[j];
            float4 sv;
            sv.x = xv.x + (qv.x - xv.x);
            sv.y = xv.y + (qv.y - xv.y);
            sv.z = xv.z + (qv.z - xv.z);
            sv.w = xv.w + (qv.w - xv.w);
            double d;
            d = (double)xv.x - (double)qv.x; acc = fma(d, d, acc);
            d = (double)xv.y - (double)qv.y; acc = fma(d, d, acc);
            d = (double)xv.z - (double)qv.z; acc = fma(d, d, acc);
            d = (double)xv.w - (double)qv.w; acc = fma(d, d, acc);
            ((float4*)oq)[j]  = qv;
            ((float4*)ost)[j] = sv;
        }
        if (!flag) mseTot += acc;
        if (half == 0) {
            out[(size_t)token * CC + c] = (float)bi;
            if (!flag) {
                atomicAdd(&s_lhist[bi], mask[token]);
            } else {
                unsigned slot = atomicAdd(count, 1u);
                if (slot < CAP) list[slot] = ((unsigned)token << 3) | (unsigned)c;
            }
        }
    }

    // ---- block reductions: mse + local hist flush ----
    #pragma unroll
    for (int off = 32; off > 0; off >>= 1)
        mseTot += __shfl_down(mseTot, off, 64);
    if (lane == 0) s_mse[wv] = mseTot;
    __syncthreads();
    if (tid == 0) {
        double s = 0.0;
        #pragma unroll
        for (int w = 0; w < 8; ++w) s += s_mse[w];
        atomicAdd(mse_sum, s);
    }
    {
        float v = s_lhist[tid];
        if (v != 0.f) atomicAdd(&hist[c * KK + tid], v);
    }
}

// ---------------------------------------------------------------------------
// Exact re-resolve: one wave per flagged (token,c). Replicates the verified
// arithmetic bit-for-bit (f64 subterms -> single f32 rounding, np first-index
// tie-break). x held in f32 REGISTERS (f32->f64 convert at use is exact, so
// the fma stream is bit-identical); no 64-VGPR double array -> no scratch.
// Grid 2048 blocks (~1 pair/wave) so per-pair latency is hidden by TLP.
__global__ __launch_bounds__(256, 2) void vq_resolve(
    const float* __restrict__ latents, const float* __restrict__ mask,
    const float* __restrict__ cbs, const float* __restrict__ csq_g,
    float* __restrict__ out, double* __restrict__ mse_sum,
    float* __restrict__ hist, const unsigned* __restrict__ count,
    const unsigned* __restrict__ list)
{
    unsigned n = *count; if (n > CAP) n = CAP;
    const int lane  = threadIdx.x & 63;
    const int wave  = (blockIdx.x << 2) | (threadIdx.x >> 6);
    const int nwav  = gridDim.x << 2;

    for (unsigned i = wave; i < n; i += nwav) {
        const unsigned e = list[i];
        const int token = (int)(e >> 3), c = (int)(e & 7u);
        const float* xp = latents + (size_t)token * DD + c * SD;

        float4 xv[8];
        #pragma unroll
        for (int j = 0; j < 8; ++j) xv[j] = ((const float4*)xp)[j];

        double xs = 0.0;
        #pragma unroll
        for (int j = 0; j < 8; ++j) {
            xs = fma((double)xv[j].x, (double)xv[j].x, xs);
            xs = fma((double)xv[j].y, (double)xv[j].y, xs);
            xs = fma((double)xv[j].z, (double)xv[j].z, xs);
            xs = fma((double)xv[j].w, (double)xv[j].w, xs);
        }
        const float xsqf = (float)xs;
        const float* cbase = cbs + (size_t)c * KK * SD;
        const float* csqc  = csq_g + c * KK;

        // lane handles k in [lane*8, lane*8+8) -> lane order == k order
        float best = 1e30f; int bk = lane * 8;
        #pragma unroll
        for (int j = 0; j < 8; ++j) {
            const int k = lane * 8 + j;
            const float4* cw = (const float4*)(cbase + k * SD);
            double d0 = 0.0, d1 = 0.0, d2 = 0.0, d3 = 0.0;
            #pragma unroll
            for (int q = 0; q < 8; ++q) {
                float4 cv = cw[q];
                d0 = fma((double)cv.x, (double)xv[q].x, d0);
                d1 = fma((double)cv.y, (double)xv[q].y, d1);
                d2 = fma((double)cv.z, (double)xv[q].z, d2);
                d3 = fma((double)cv.w, (double)xv[q].w, d3);
            }
            const float dotf = (float)((d0 + d1) + (d2 + d3));
            const float t1 = xsqf + csqc[k];
            const float dist = t1 - 2.0f * dotf;
            if (dist < best) { best = dist; bk = k; }
        }
        #pragma unroll
        for (int off = 32; off > 0; off >>= 1) {
            float od = __shfl_down(best, off, 64);
            int   ok = __shfl_down(bk,   off, 64);
            if (od < best || (od == best && ok < bk)) { best = od; bk = ok; }
        }
        bk = __shfl(bk, 0, 64);

        const int oldid = (int)out[(size_t)token * CC + c];
        if (bk != oldid) {
            if (lane == 0) out[(size_t)token * CC + c] = (float)bk;
            if (lane < SD) {
                float q = cbase[bk * SD + lane];
                float x = xp[lane];
                out[OFF_Q  + (size_t)token * DD + c * SD + lane] = q;
                out[OFF_ST + (size_t)token * DD + c * SD + lane] = x + (q - x);
            }
        }
        double dd = 0.0;
        if (lane < SD) {
            double q = (double)cbase[bk * SD + lane];
            double df = (double)xp[lane] - q;
            dd = df * df;
        }
        #pragma unroll
        for (int off = 32; off > 0; off >>= 1) dd += __shfl_down(dd, off, 64);
        if (lane == 0) {
            atomicAdd(mse_sum, dd);
            atomicAdd(&hist[c * KK + bk], mask[token]);
        }
    }
}

// ---------------------------------------------------------------------------
__global__ __launch_bounds__(512) void vq_final(
    const float* __restrict__ hist, const double* __restrict__ mse_sum,
    const double* __restrict__ mask_sum, float* __restrict__ out)
{
    __shared__ double ent[CC];
    const int tid = threadIdx.x;
    double denom = *mask_sum; if (denom < 1.0) denom = 1.0;

    const int w = tid >> 6;
    const int lane = tid & 63;
    double t = 0.0;
    for (int k = lane; k < KK; k += 64) {
        double p = (double)hist[w * KK + k] / denom;
        t += p * log(p + 1e-8);
    }
    #pragma unroll
    for (int off = 32; off > 0; off >>= 1) t += __shfl_down(t, off, 64);
    if (lane == 0) ent[w] = -t;
    __syncthreads();

    if (tid == 0) {
        double mean = mse_sum[0] / (double)QN;
        out[OFF_SC + 0] = (float)(0.25 * mean);
        out[OFF_SC + 1] = (float)(1.0 * mean);
        double perp = 0.0;
        for (int cc = 0; cc < CC; ++cc) perp += exp(ent[cc]);
        out[OFF_SC + 2] = (float)(perp / (double)CC);
    }
}

extern "C" void kernel_launch(void* const* d_in, const int* in_sizes, int n_in,
                              void* d_out, int out_size, void* d_ws, size_t ws_size,
                              hipStream_t stream) {
    const float* latents = (const float*)d_in[0];
    const float* mask    = (const float*)d_in[1];
    const float* cbs     = (const float*)d_in[2];
    float* out = (float*)d_out;

    double*   mse      = (double*)d_ws;
    double*   mask_sum = (double*)((char*)d_ws + 8);
    unsigned* count    = (unsigned*)((char*)d_ws + 16);
    float*    hist     = (float*)((char*)d_ws + 32);
    float*    csqf     = (float*)((char*)d_ws + 32 + 16384);
    unsigned* list     = (unsigned*)((char*)d_ws + 32 + 32768);

    hipMemsetAsync(d_ws, 0, WS_ZERO, stream);

    vq_prep<<<dim3(16), dim3(256), 0, stream>>>(cbs, mask, csqf, mask_sum);
    vq_score<<<dim3(512), dim3(512), 0, stream>>>(
        latents, mask, cbs, csqf, out, mse, hist, count, list);
    vq_resolve<<<dim3(2048), dim3(256), 0, stream>>>(
        latents, mask, cbs, csqf, out, mse, hist, count, list);
    vq_final<<<dim3(1), dim3(512), 0, stream>>>(hist, mse, mask_sum, out);
}

// Round 3
// 348.533 us; speedup vs baseline: 1.8408x; 1.1774x over previous
//
#include <hip/hip_runtime.h>
#include <math.h>

// Problem constants
#define BB 16
#define NN 4096
#define DD 256
#define CC 8
#define KK 512
#define SD 32
#define NTOK (BB * NN)            // 65536
#define IDS_N (NTOK * CC)         // 524288
#define QN (NTOK * DD)            // 16777216
#define OFF_Q   (IDS_N)
#define OFF_ST  (IDS_N + QN)
#define OFF_SC  (IDS_N + 2 * QN)

// Margin gate: split-bf16 3-MFMA score error <= ~8e-6 worst case; np-vs-exact
// flip requires exact gap <= ~1.6e-5. Unflagged => fast gap >= GUARD =>
// exact gap >= 6e-5 - 1.6e-5 = 4.4e-5 > 1.6e-5 (2.7x margin). ~1.5% flagged.
#define GUARD 6e-5f
#define CAP 65536

// ws layout
// 0:   double mse_sum
// 8:   double mask_sum
// 16:  unsigned flag_count (+pad)
// 32:  float hist[CC*KK]            (16384 B)
// 32+16384: float csqf[CC*KK]       (16384 B)
// 32+32768: unsigned list[CAP]      (262144 B)
#define WS_ZERO (32 + 16384)

typedef float f32x4 __attribute__((ext_vector_type(4)));
typedef short s16x8 __attribute__((ext_vector_type(8)));

__device__ __forceinline__ unsigned short f2bf(float f) {
    unsigned u = __float_as_uint(f);
    u += 0x7fffu + ((u >> 16) & 1u);
    return (unsigned short)(u >> 16);
}
__device__ __forceinline__ float bf2f(unsigned short h) {
    return __uint_as_float(((unsigned)h) << 16);
}
// split f32x8 -> bf16 hi + bf16 lo (x ~= hi + lo, exact to 2^-16 rel)
__device__ __forceinline__ void split8(const float4 a, const float4 b,
                                       s16x8& hv, s16x8& lv) {
    unsigned short h;
    h = f2bf(a.x); hv[0]=(short)h; lv[0]=(short)f2bf(a.x - bf2f(h));
    h = f2bf(a.y); hv[1]=(short)h; lv[1]=(short)f2bf(a.y - bf2f(h));
    h = f2bf(a.z); hv[2]=(short)h; lv[2]=(short)f2bf(a.z - bf2f(h));
    h = f2bf(a.w); hv[3]=(short)h; lv[3]=(short)f2bf(a.w - bf2f(h));
    h = f2bf(b.x); hv[4]=(short)h; lv[4]=(short)f2bf(b.x - bf2f(h));
    h = f2bf(b.y); hv[5]=(short)h; lv[5]=(short)f2bf(b.y - bf2f(h));
    h = f2bf(b.z); hv[6]=(short)h; lv[6]=(short)f2bf(b.z - bf2f(h));
    h = f2bf(b.w); hv[7]=(short)h; lv[7]=(short)f2bf(b.w - bf2f(h));
}

// ---------------------------------------------------------------------------
// Prep: csq (f64-accurate -> f32, same fma order as the verified kernel),
// plus parallel mask-sum.
__global__ __launch_bounds__(256) void vq_prep(
    const float* __restrict__ cbs, const float* __restrict__ mask,
    float* __restrict__ csqf, double* __restrict__ mask_sum)
{
    __shared__ double red[256];
    const int tid = threadIdx.x;
    const int cell = blockIdx.x * 256 + tid;     // 16 blocks -> 4096 cells
    const float* cp = cbs + (size_t)cell * SD;
    double s = 0.0;
    #pragma unroll
    for (int j = 0; j < 8; ++j) {
        float4 v = ((const float4*)cp)[j];
        double a = (double)v.x, b = (double)v.y, c = (double)v.z, d = (double)v.w;
        s = fma(a, a, s); s = fma(b, b, s);
        s = fma(c, c, s); s = fma(d, d, s);
    }
    csqf[cell] = (float)s;

    double m = 0.0;
    for (int i = cell; i < NTOK; i += 4096) m += (double)mask[i];
    red[tid] = m;
    __syncthreads();
    for (int st = 128; st > 0; st >>= 1) {
        if (tid < st) red[tid] += red[tid + st];
        __syncthreads();
    }
    if (tid == 0) atomicAdd(mask_sum, red[0]);
}

// ---------------------------------------------------------------------------
// MFMA fast pass, ids + flags + hist ONLY (Q/ST/mse moved to vq_emit).
// Block = 512 thr (8 waves), one codebook c, 1024-token slab, 4 passes of
// 8x32 tokens. Codebook staged in LDS as split-bf16 with 16B-sub-block XOR
// swizzle. X for pass p+1 prefetched before pass p's MFMA loop.
__global__ __launch_bounds__(512, 4) void vq_score(
    const float* __restrict__ latents, const float* __restrict__ mask,
    const float* __restrict__ cbs, const float* __restrict__ csq_g,
    float* __restrict__ out, float* __restrict__ hist,
    unsigned* __restrict__ count, unsigned* __restrict__ list)
{
    __shared__ unsigned short s_hi[KK * SD];   // 32 KB
    __shared__ unsigned short s_lo[KK * SD];   // 32 KB
    __shared__ float  s_csq[KK];               // 2 KB
    __shared__ float  s_lhist[KK];             // 2 KB
    __shared__ float  s_best[8][32];
    __shared__ float  s_sec[8][32];
    __shared__ int    s_bid[8][32];

    const int tid = threadIdx.x;
    const int c   = blockIdx.x & 7;
    const int tb  = blockIdx.x >> 3;           // 0..63

    // ---- stage codebook c (split-bf16, swizzled) + csq + zero local hist ----
    {
        const int cw = tid;                    // 512 threads == KK codewords
        const float* cp = cbs + ((size_t)c * KK + cw) * SD;
        s_csq[cw] = csq_g[c * KK + cw];
        s_lhist[cw] = 0.f;
        const int sw = (cw >> 1) & 3;
        #pragma unroll
        for (int q = 0; q < 4; ++q) {
            float4 a = ((const float4*)cp)[2 * q];
            float4 b = ((const float4*)cp)[2 * q + 1];
            s16x8 hv, lv;
            split8(a, b, hv, lv);
            ((s16x8*)(s_hi + (size_t)cw * SD))[q ^ sw] = hv;
            ((s16x8*)(s_lo + (size_t)cw * SD))[q ^ sw] = lv;
        }
    }
    __syncthreads();

    const int wv   = tid >> 6;                 // wave 0..7
    const int lane = tid & 63;
    const int col  = lane & 15;                // A-row / B-col / C-col
    const int kb   = lane >> 4;                // k-group 0..3

    // prefetch pass-0 X
    float4 xa[2][2];
    #pragma unroll
    for (int t = 0; t < 2; ++t) {
        const int token = tb * 1024 + wv * 32 + t * 16 + col;
        const float4* xp =
            (const float4*)(latents + (size_t)token * DD + c * SD + kb * 8);
        xa[t][0] = xp[0]; xa[t][1] = xp[1];
    }

    #pragma unroll 1
    for (int p = 0; p < 4; ++p) {
        const int tok0 = tb * 1024 + p * 256 + wv * 32;

        // consume prefetched X into A fragments
        s16x8 ah[2], al[2];
        #pragma unroll
        for (int t = 0; t < 2; ++t) split8(xa[t][0], xa[t][1], ah[t], al[t]);

        // issue next-pass X loads; they land under the nt loop
        if (p < 3) {
            #pragma unroll
            for (int t = 0; t < 2; ++t) {
                const int token = tb * 1024 + (p + 1) * 256 + wv * 32 + t * 16 + col;
                const float4* xp =
                    (const float4*)(latents + (size_t)token * DD + c * SD + kb * 8);
                xa[t][0] = xp[0]; xa[t][1] = xp[1];
            }
        }

        float best[2][4], sec[2][4]; int bid[2][4];
        #pragma unroll
        for (int t = 0; t < 2; ++t)
            #pragma unroll
            for (int r = 0; r < 4; ++r) {
                best[t][r] = 1e30f; sec[t][r] = 1e30f; bid[t][r] = 0;
            }

        for (int nt = 0; nt < 32; ++nt) {
            const int kcol = nt * 16 + col;    // this lane's codeword column
            const int slot = kb ^ ((kcol >> 1) & 3);
            const float cs = s_csq[kcol];
            const s16x8 bh = *((const s16x8*)(s_hi + (size_t)kcol * SD + slot * 8));
            const s16x8 bl = *((const s16x8*)(s_lo + (size_t)kcol * SD + slot * 8));
            #pragma unroll
            for (int t = 0; t < 2; ++t) {
                f32x4 acc = {0.f, 0.f, 0.f, 0.f};
                acc = __builtin_amdgcn_mfma_f32_16x16x32_bf16(ah[t], bh, acc, 0, 0, 0);
                acc = __builtin_amdgcn_mfma_f32_16x16x32_bf16(ah[t], bl, acc, 0, 0, 0);
                acc = __builtin_amdgcn_mfma_f32_16x16x32_bf16(al[t], bh, acc, 0, 0, 0);
                // acc[r] = dot(token row kb*4+r, codeword kcol)
                #pragma unroll
                for (int r = 0; r < 4; ++r) {
                    const float s = fmaf(-2.f, acc[r], cs);
                    const bool lt = s < best[t][r];
                    bid[t][r]  = lt ? kcol : bid[t][r];
                    // invariant sec >= best: median(s, best, sec) = new runner-up
                    sec[t][r]  = __builtin_amdgcn_fmed3f(s, best[t][r], sec[t][r]);
                    best[t][r] = fminf(best[t][r], s);
                }
            }
        }

        // merge top-2 across the 16 lanes of each kb-group (exact ties ->
        // gap 0 -> flagged, so tie semantics are safe)
        #pragma unroll
        for (int m = 1; m <= 8; m <<= 1) {
            #pragma unroll
            for (int t = 0; t < 2; ++t)
                #pragma unroll
                for (int r = 0; r < 4; ++r) {
                    const float ob = __shfl_xor(best[t][r], m, 64);
                    const float os = __shfl_xor(sec[t][r],  m, 64);
                    const int   oi = __shfl_xor(bid[t][r],  m, 64);
                    const float ns = fminf(fmaxf(best[t][r], ob),
                                           fminf(sec[t][r], os));
                    const bool tk = (ob < best[t][r]) ||
                                    (ob == best[t][r] && oi < bid[t][r]);
                    bid[t][r]  = tk ? oi : bid[t][r];
                    best[t][r] = fminf(best[t][r], ob);
                    sec[t][r]  = ns;
                }
        }

        // publish per-token results to wave-private LDS scratch
        asm volatile("s_waitcnt lgkmcnt(0)" ::: "memory");
        if (col == 0) {
            #pragma unroll
            for (int t = 0; t < 2; ++t)
                #pragma unroll
                for (int r = 0; r < 4; ++r) {
                    const int idx = t * 16 + kb * 4 + r;
                    s_best[wv][idx] = best[t][r];
                    s_sec[wv][idx]  = sec[t][r];
                    s_bid[wv][idx]  = bid[t][r];
                }
        }
        asm volatile("s_waitcnt lgkmcnt(0)" ::: "memory");

        // ---- tail: 1 lane per token -> ids + flag/hist ----
        if (lane < 32) {
            const int token = tok0 + lane;
            const float bb  = s_best[wv][lane];
            const float ssv = s_sec[wv][lane];
            const int   bi  = s_bid[wv][lane];
            const bool flag = (ssv - bb) < GUARD;
            out[(size_t)token * CC + c] = (float)bi;
            if (!flag) {
                atomicAdd(&s_lhist[bi], mask[token]);
            } else {
                unsigned slot = atomicAdd(count, 1u);
                if (slot < CAP) list[slot] = ((unsigned)token << 3) | (unsigned)c;
            }
        }
    }

    // ---- local hist flush ----
    __syncthreads();
    {
        float v = s_lhist[tid];
        if (v != 0.f) atomicAdd(&hist[c * KK + tid], v);
    }
}

// ---------------------------------------------------------------------------
// Exact re-resolve, coalesced: 64 lanes = 8 codewords x 8 dim-quads, so every
// codeword load instruction covers 1024 contiguous bytes (vs 64 scattered
// lines before -> ~50x fewer L2 requests). f64 products exact; summation-order
// change vs the chain version is ~1e-13 abs, 9 orders below the f32 dist
// quantum. dist formula + first-index tie-break preserved. Patches ids + hist
// only (Q/ST/mse now owned by vq_emit, which runs after).
__global__ __launch_bounds__(256) void vq_resolve(
    const float* __restrict__ latents, const float* __restrict__ mask,
    const float* __restrict__ cbs, const float* __restrict__ csq_g,
    float* __restrict__ out, float* __restrict__ hist,
    const unsigned* __restrict__ count, const unsigned* __restrict__ list)
{
    unsigned n = *count; if (n > CAP) n = CAP;
    const int lane = threadIdx.x & 63;
    const int wave = (blockIdx.x << 2) | (threadIdx.x >> 6);
    const int nwav = gridDim.x << 2;
    const int dq = lane & 7;                   // dim quad 0..7
    const int kk = lane >> 3;                  // codeword sub-index 0..7

    for (unsigned i = wave; i < n; i += nwav) {
        const unsigned e = list[i];
        const int token = (int)(e >> 3), c = (int)(e & 7u);
        const float* xp = latents + (size_t)token * DD + c * SD;

        const float4 xq = ((const float4*)xp)[dq];
        const double x0 = (double)xq.x, x1 = (double)xq.y;
        const double x2 = (double)xq.z, x3 = (double)xq.w;

        double px = fma(x3, x3, fma(x2, x2, fma(x1, x1, x0 * x0)));
        px += __shfl_xor(px, 1, 64);
        px += __shfl_xor(px, 2, 64);
        px += __shfl_xor(px, 4, 64);
        const float xsqf = (float)px;

        const float* cbase = cbs + (size_t)c * KK * SD;
        const float* csqc  = csq_g + c * KK;

        float best = 1e30f; int bk = kk;
        #pragma unroll 4
        for (int jk = 0; jk < 64; ++jk) {
            const int k = jk * 8 + kk;
            const float4 cv = ((const float4*)(cbase + (size_t)k * SD))[dq];
            double d = fma((double)cv.w, x3, fma((double)cv.z, x2,
                       fma((double)cv.y, x1, (double)cv.x * x0)));
            d += __shfl_xor(d, 1, 64);
            d += __shfl_xor(d, 2, 64);
            d += __shfl_xor(d, 4, 64);
            const float dotf = (float)d;
            const float t1 = xsqf + csqc[k];
            const float dist = t1 - 2.0f * dotf;
            // k ascending within this lane's subset -> strict < = first index
            if (dist < best) { best = dist; bk = k; }
        }
        // merge the 8 kk-groups (lanes within a group are identical)
        #pragma unroll
        for (int m = 8; m <= 32; m <<= 1) {
            const float od = __shfl_xor(best, m, 64);
            const int   ok = __shfl_xor(bk,   m, 64);
            if (od < best || (od == best && ok < bk)) { best = od; bk = ok; }
        }
        if (lane == 0) {
            out[(size_t)token * CC + c] = (float)bk;
            atomicAdd(&hist[c * KK + bk], mask[token]);
        }
    }
}

// ---------------------------------------------------------------------------
// Emit: memory-bound pass over all tokens using FINAL ids. Lane l of a wave
// owns dims [l*4, l*4+4) of one token (c = l>>3, dq = l&7) -> x load, Q/ST
// stores are contiguous 1 KB per wave; codeword gather is 8 lines/wave.
// Also accumulates the full f64 mse (order-free: f64 error << f32 ulp).
__global__ __launch_bounds__(256) void vq_emit(
    const float* __restrict__ latents, const float* __restrict__ cbs,
    float* __restrict__ out, double* __restrict__ mse_sum)
{
    __shared__ double s_red[4];
    const int tid  = threadIdx.x;
    const int lane = tid & 63;
    const int wv   = tid >> 6;
    const int c    = lane >> 3;
    const int dq   = lane & 7;
    const int wave = blockIdx.x * 4 + wv;      // 8192 waves

    double acc = 0.0;
    for (int token = wave; token < NTOK; token += 8192) {
        const int bi = (int)out[(size_t)token * CC + c];
        const float4 xq = ((const float4*)(latents + (size_t)token * DD))[lane];
        const float4 qv = ((const float4*)(cbs + ((size_t)c * KK + bi) * SD))[dq];
        float4 sv;
        sv.x = xq.x + (qv.x - xq.x);
        sv.y = xq.y + (qv.y - xq.y);
        sv.z = xq.z + (qv.z - xq.z);
        sv.w = xq.w + (qv.w - xq.w);
        ((float4*)(out + OFF_Q  + (size_t)token * DD))[lane] = qv;
        ((float4*)(out + OFF_ST + (size_t)token * DD))[lane] = sv;
        double d;
        d = (double)xq.x - (double)qv.x; acc = fma(d, d, acc);
        d = (double)xq.y - (double)qv.y; acc = fma(d, d, acc);
        d = (double)xq.z - (double)qv.z; acc = fma(d, d, acc);
        d = (double)xq.w - (double)qv.w; acc = fma(d, d, acc);
    }
    #pragma unroll
    for (int off = 32; off > 0; off >>= 1) acc += __shfl_down(acc, off, 64);
    if (lane == 0) s_red[wv] = acc;
    __syncthreads();
    if (tid == 0)
        atomicAdd(mse_sum, s_red[0] + s_red[1] + s_red[2] + s_red[3]);
}

// ---------------------------------------------------------------------------
__global__ __launch_bounds__(512) void vq_final(
    const float* __restrict__ hist, const double* __restrict__ mse_sum,
    const double* __restrict__ mask_sum, float* __restrict__ out)
{
    __shared__ double ent[CC];
    const int tid = threadIdx.x;
    double denom = *mask_sum; if (denom < 1.0) denom = 1.0;

    const int w = tid >> 6;
    const int lane = tid & 63;
    double t = 0.0;
    for (int k = lane; k < KK; k += 64) {
        double p = (double)hist[w * KK + k] / denom;
        t += p * log(p + 1e-8);
    }
    #pragma unroll
    for (int off = 32; off > 0; off >>= 1) t += __shfl_down(t, off, 64);
    if (lane == 0) ent[w] = -t;
    __syncthreads();

    if (tid == 0) {
        double mean = mse_sum[0] / (double)QN;
        out[OFF_SC + 0] = (float)(0.25 * mean);
        out[OFF_SC + 1] = (float)(1.0 * mean);
        double perp = 0.0;
        for (int cc = 0; cc < CC; ++cc) perp += exp(ent[cc]);
        out[OFF_SC + 2] = (float)(perp / (double)CC);
    }
}

extern "C" void kernel_launch(void* const* d_in, const int* in_sizes, int n_in,
                              void* d_out, int out_size, void* d_ws, size_t ws_size,
                              hipStream_t stream) {
    const float* latents = (const float*)d_in[0];
    const float* mask    = (const float*)d_in[1];
    const float* cbs     = (const float*)d_in[2];
    float* out = (float*)d_out;

    double*   mse      = (double*)d_ws;
    double*   mask_sum = (double*)((char*)d_ws + 8);
    unsigned* count    = (unsigned*)((char*)d_ws + 16);
    float*    hist     = (float*)((char*)d_ws + 32);
    float*    csqf     = (float*)((char*)d_ws + 32 + 16384);
    unsigned* list     = (unsigned*)((char*)d_ws + 32 + 32768);

    hipMemsetAsync(d_ws, 0, WS_ZERO, stream);

    vq_prep<<<dim3(16), dim3(256), 0, stream>>>(cbs, mask, csqf, mask_sum);
    vq_score<<<dim3(512), dim3(512), 0, stream>>>(
        latents, mask, cbs, csqf, out, hist, count, list);
    vq_resolve<<<dim3(2048), dim3(256), 0, stream>>>(
        latents, mask, cbs, csqf, out, hist, count, list);
    vq_emit<<<dim3(2048), dim3(256), 0, stream>>>(latents, cbs, out, mse);
    vq_final<<<dim3(1), dim3(512), 0, stream>>>(hist, mse, mask_sum, out);
}